// Round 2
// baseline (672.954 us; speedup 1.0000x reference)
//
#include <hip/hip_runtime.h>
#include <stdint.h>

#define NN 8192
#define DD 512
#define SPLIT 4
#define ITERS_PER_SPLIT 16   // 64 total K-iters of 128 / SPLIT

typedef uint16_t u16;
typedef __bf16 bf16x8_t __attribute__((ext_vector_type(8)));
typedef float f32x4_t __attribute__((ext_vector_type(4)));

__device__ __forceinline__ u16 f2bf(float x) {
  uint32_t u = __builtin_bit_cast(uint32_t, x);
  u += 0x7FFFu + ((u >> 16) & 1u);   // round-to-nearest-even
  return (u16)(u >> 16);
}

__device__ __forceinline__ unsigned encf(float f) {
  unsigned u = __builtin_bit_cast(unsigned, f);
  return (u & 0x80000000u) ? ~u : (u | 0x80000000u);
}
__device__ __forceinline__ float decf(unsigned e) {
  unsigned u = (e & 0x80000000u) ? (e & 0x7FFFFFFFu) : ~e;
  return __builtin_bit_cast(float, u);
}

// ---------------------------------------------------------------- convert input f32 -> bf16
__global__ __launch_bounds__(256) void k_convert_input(const float* __restrict__ in,
                                                       u16* __restrict__ out) {
  int idx = blockIdx.x * blockDim.x + threadIdx.x;  // one per 4 elems
  float4 v = ((const float4*)in)[idx];
  ushort4 o;
  o.x = f2bf(v.x); o.y = f2bf(v.y); o.z = f2bf(v.z); o.w = f2bf(v.w);
  ((ushort4*)out)[idx] = o;
}

// ---------------------------------------------------------------- W[k][n] -> WT[n][k] bf16, init maxenc
__global__ __launch_bounds__(256) void k_convert_W(const float* __restrict__ W,
                                                   u16* __restrict__ WT,
                                                   unsigned* __restrict__ maxenc) {
  int t = blockIdx.x * blockDim.x + threadIdx.x;  // 32768 threads
  if (t == 0) *maxenc = 0u;
  int n = t >> 6;
  int k8 = (t & 63) << 3;
  u16 tmp[8];
#pragma unroll
  for (int j = 0; j < 8; ++j) tmp[j] = f2bf(W[(size_t)(k8 + j) * DD + n]);
  uint32_t w0 = (uint32_t)tmp[0] | ((uint32_t)tmp[1] << 16);
  uint32_t w1 = (uint32_t)tmp[2] | ((uint32_t)tmp[3] << 16);
  uint32_t w2 = (uint32_t)tmp[4] | ((uint32_t)tmp[5] << 16);
  uint32_t w3 = (uint32_t)tmp[6] | ((uint32_t)tmp[7] << 16);
  *(uint4*)&WT[(size_t)n * DD + k8] = make_uint4(w0, w1, w2, w3);
}

// ---------------------------------------------------------------- h = input @ W  (bf16 MFMA, f32 out)
__global__ __launch_bounds__(256) void k_gemm_h(const u16* __restrict__ A,
                                                const u16* __restrict__ BT,
                                                float* __restrict__ H) {
  __shared__ __align__(16) u16 As[128 * 32];
  __shared__ __align__(16) u16 Bs[128 * 32];
  const int tid = threadIdx.x;
  const int wid = tid >> 6, lane = tid & 63;
  const int wr = wid >> 1, wc = wid & 1;
  const int lr = lane & 15, kg = lane >> 4;
  const int rowBase = blockIdx.x * 128;
  const int colBase = blockIdx.y * 128;
  const int sr = tid >> 2, sc = tid & 3;
  f32x4_t acc[4][4] = {};
  for (int kt = 0; kt < 16; ++kt) {
    const int k0 = kt * 32 + sc * 8;
    *(uint4*)&As[tid * 8] = *(const uint4*)&A[(size_t)(rowBase + sr) * DD + k0];
    *(uint4*)&Bs[tid * 8] = *(const uint4*)&BT[(size_t)(colBase + sr) * DD + k0];
    *(uint4*)&As[(tid + 256) * 8] = *(const uint4*)&A[(size_t)(rowBase + 64 + sr) * DD + k0];
    *(uint4*)&Bs[(tid + 256) * 8] = *(const uint4*)&BT[(size_t)(colBase + 64 + sr) * DD + k0];
    __syncthreads();
    bf16x8_t af[4], bfv[4];
#pragma unroll
    for (int mt = 0; mt < 4; ++mt)
      af[mt] = *(const bf16x8_t*)&As[(wr * 64 + mt * 16 + lr) * 32 + kg * 8];
#pragma unroll
    for (int nt = 0; nt < 4; ++nt)
      bfv[nt] = *(const bf16x8_t*)&Bs[(wc * 64 + nt * 16 + lr) * 32 + kg * 8];
#pragma unroll
    for (int mt = 0; mt < 4; ++mt)
#pragma unroll
      for (int nt = 0; nt < 4; ++nt)
        acc[mt][nt] = __builtin_amdgcn_mfma_f32_16x16x32_bf16(af[mt], bfv[nt], acc[mt][nt], 0, 0, 0);
    __syncthreads();
  }
#pragma unroll
  for (int mt = 0; mt < 4; ++mt)
#pragma unroll
    for (int nt = 0; nt < 4; ++nt)
#pragma unroll
      for (int r = 0; r < 4; ++r)
        H[(size_t)(rowBase + wr * 64 + mt * 16 + kg * 4 + r) * DD + colBase + wc * 64 + nt * 16 + lr] =
            acc[mt][nt][r];
}

// ---------------------------------------------------------------- e1/e2 per row (f32), maxE2 via encoded atomicMax
__global__ __launch_bounds__(256) void k_e12(const float* __restrict__ H,
                                             const float* __restrict__ a1,
                                             const float* __restrict__ a2,
                                             float* __restrict__ e1, float* __restrict__ e2,
                                             unsigned* __restrict__ maxenc) {
  const int wid = threadIdx.x >> 6, lane = threadIdx.x & 63;
  const int row = blockIdx.x * 4 + wid;
  const float* hr = H + (size_t)row * DD;
  float s1 = 0.f, s2 = 0.f;
#pragma unroll
  for (int base = 0; base < DD; base += 256) {
    float4 hv = *(const float4*)&hr[base + lane * 4];
    float4 v1 = *(const float4*)&a1[base + lane * 4];
    float4 v2 = *(const float4*)&a2[base + lane * 4];
    s1 += hv.x * v1.x + hv.y * v1.y + hv.z * v1.z + hv.w * v1.w;
    s2 += hv.x * v2.x + hv.y * v2.y + hv.z * v2.z + hv.w * v2.w;
  }
#pragma unroll
  for (int off = 32; off >= 1; off >>= 1) {
    s1 += __shfl_down(s1, off);
    s2 += __shfl_down(s2, off);
  }
  if (lane == 0) {
    e1[row] = s1;
    e2[row] = s2;
    atomicMax(maxenc, encf(s2));
  }
}

// ---------------------------------------------------------------- H f32 [8192][512] -> HT bf16 [512][8192]
__global__ __launch_bounds__(256) void k_transpose(const float* __restrict__ H,
                                                   u16* __restrict__ HT) {
  __shared__ float tile[32][33];
  const int r0 = blockIdx.x * 32;
  const int c0 = blockIdx.y * 32;
  const int tx = threadIdx.x & 31;
  const int ty = threadIdx.x >> 5;  // 0..7
#pragma unroll
  for (int i = 0; i < 4; ++i) {
    int r = ty + i * 8;
    tile[r][tx] = H[(size_t)(r0 + r) * DD + c0 + tx];
  }
  __syncthreads();
#pragma unroll
  for (int i = 0; i < 4; ++i) {
    int c = ty + i * 8;
    HT[(size_t)(c0 + c) * NN + r0 + tx] = f2bf(tile[tx][c]);
  }
}

// ---------------------------------------------------------------- fused masked-softmax @ h (split-K partials)
// grid (256, SPLIT) x 512 threads. Block owns 32 rows x 2048 K-cols (16 iters of 128).
// P stored in LDS in MFMA-fragment-linear order: unit tau = mt*256 + c*16 + m  (c = ks*4+kg),
// so both ds_write (tau = tid) and ds_read (addr = mt*4096 + ks*1024 + lane*16) are linear.
__global__ __launch_bounds__(512, 8) void k_fused(const float* __restrict__ adj,
                                                  const u16* __restrict__ HT,
                                                  const float* __restrict__ e1,
                                                  const float* __restrict__ e2,
                                                  const unsigned* __restrict__ maxenc,
                                                  float* __restrict__ numpart,
                                                  float* __restrict__ denpart) {
  __shared__ __align__(16) u16 P[2][32 * 128];
  __shared__ float partsum[512];
  __shared__ float denom[32];
  const int tid = threadIdx.x;
  const int wid = tid >> 6;
  const int lane = tid & 63;
  const int lr = lane & 15;
  const int kg = lane >> 4;
  const int rowBase = blockIdx.x * 32;
  const int bz = blockIdx.y;
  const int kk0 = bz * ITERS_PER_SPLIT;
  // P-build task coords (fixed per thread; each thread owns one row's 8-col slab per iter)
  const int pmt = tid >> 8;        // 0..1
  const int pc = (tid >> 4) & 15;  // 0..15 -> 8-col chunk
  const int pm = tid & 15;
  const int prow = rowBase + pmt * 16 + pm;
  const float e1r = e1[prow];
  const float mE2 = decf(*maxenc);
  const float xb = e1r + mE2;
  const float bnd = fmaxf(xb, 0.2f * xb);  // leakyrelu(e1+maxE2) >= all row scores
  float dsum = 0.f;
  const float* adjp = adj + (size_t)prow * NN + pc * 8;
  const float* e2p = e2 + pc * 8;
  const int n0 = wid * 64;
  const u16* btp0 = HT + (size_t)(n0 + 0 + lr) * NN + kg * 8;
  const u16* btp1 = HT + (size_t)(n0 + 16 + lr) * NN + kg * 8;
  const u16* btp2 = HT + (size_t)(n0 + 32 + lr) * NN + kg * 8;
  const u16* btp3 = HT + (size_t)(n0 + 48 + lr) * NN + kg * 8;
  f32x4_t acc[2][4] = {};
  for (int t = 0; t < ITERS_PER_SPLIT; ++t) {
    const int kk = kk0 + t;
    const int colBase = kk * 128;
    float4 av0 = *(const float4*)(adjp + colBase);
    float4 av1 = *(const float4*)(adjp + colBase + 4);
    float4 ev0 = *(const float4*)(e2p + colBase);
    float4 ev1 = *(const float4*)(e2p + colBase + 4);
    float aa[8] = {av0.x, av0.y, av0.z, av0.w, av1.x, av1.y, av1.z, av1.w};
    float ee[8] = {ev0.x, ev0.y, ev0.z, ev0.w, ev1.x, ev1.y, ev1.z, ev1.w};
    float pv[8];
#pragma unroll
    for (int j = 0; j < 8; ++j) {
      float x = e1r + ee[j];
      float s = fmaxf(x, 0.2f * x);                       // leakyrelu
      float p = (aa[j] > -1e19f) ? __expf(s - bnd) : 0.f; // mask: adj==0 means edge
      pv[j] = p;
      dsum += p;
    }
    uint32_t w0 = (uint32_t)f2bf(pv[0]) | ((uint32_t)f2bf(pv[1]) << 16);
    uint32_t w1 = (uint32_t)f2bf(pv[2]) | ((uint32_t)f2bf(pv[3]) << 16);
    uint32_t w2 = (uint32_t)f2bf(pv[4]) | ((uint32_t)f2bf(pv[5]) << 16);
    uint32_t w3 = (uint32_t)f2bf(pv[6]) | ((uint32_t)f2bf(pv[7]) << 16);
    *(uint4*)&P[t & 1][tid * 8] = make_uint4(w0, w1, w2, w3);
    __syncthreads();
    const u16* pb = &P[t & 1][0];
#pragma unroll
    for (int ks = 0; ks < 4; ++ks) {
      bf16x8_t a0 = *(const bf16x8_t*)(pb + ks * 512 + lane * 8);
      bf16x8_t a1f = *(const bf16x8_t*)(pb + 2048 + ks * 512 + lane * 8);
      const int co = colBase + ks * 32;
      bf16x8_t b0 = *(const bf16x8_t*)(btp0 + co);
      bf16x8_t b1 = *(const bf16x8_t*)(btp1 + co);
      bf16x8_t b2 = *(const bf16x8_t*)(btp2 + co);
      bf16x8_t b3 = *(const bf16x8_t*)(btp3 + co);
      acc[0][0] = __builtin_amdgcn_mfma_f32_16x16x32_bf16(a0, b0, acc[0][0], 0, 0, 0);
      acc[0][1] = __builtin_amdgcn_mfma_f32_16x16x32_bf16(a0, b1, acc[0][1], 0, 0, 0);
      acc[0][2] = __builtin_amdgcn_mfma_f32_16x16x32_bf16(a0, b2, acc[0][2], 0, 0, 0);
      acc[0][3] = __builtin_amdgcn_mfma_f32_16x16x32_bf16(a0, b3, acc[0][3], 0, 0, 0);
      acc[1][0] = __builtin_amdgcn_mfma_f32_16x16x32_bf16(a1f, b0, acc[1][0], 0, 0, 0);
      acc[1][1] = __builtin_amdgcn_mfma_f32_16x16x32_bf16(a1f, b1, acc[1][1], 0, 0, 0);
      acc[1][2] = __builtin_amdgcn_mfma_f32_16x16x32_bf16(a1f, b2, acc[1][2], 0, 0, 0);
      acc[1][3] = __builtin_amdgcn_mfma_f32_16x16x32_bf16(a1f, b3, acc[1][3], 0, 0, 0);
    }
  }
  // deterministic per-row denominator reduction (16 partials per row, fixed order)
  partsum[tid] = dsum;
  __syncthreads();
  if (tid < 32) {
    const int emt = tid >> 4, em = tid & 15;
    float s = 0.f;
#pragma unroll
    for (int cc = 0; cc < 16; ++cc) s += partsum[emt * 256 + cc * 16 + em];
    denpart[(size_t)bz * NN + rowBase + tid] = s;
  }
  float* np = numpart + (size_t)bz * NN * DD;
#pragma unroll
  for (int mt = 0; mt < 2; ++mt)
#pragma unroll
    for (int nt = 0; nt < 4; ++nt)
#pragma unroll
      for (int r = 0; r < 4; ++r) {
        const int rowL = mt * 16 + kg * 4 + r;
        np[(size_t)(rowBase + rowL) * DD + n0 + nt * 16 + lr] = acc[mt][nt][r];
      }
}

// ---------------------------------------------------------------- combine partials: out = tanh(num/den)
__global__ __launch_bounds__(256) void k_combine(const float* __restrict__ num,
                                                 const float* __restrict__ den,
                                                 float* __restrict__ out) {
  const size_t idx = (size_t)blockIdx.x * 256 + threadIdx.x;  // float4 units
  const int row = (int)(idx >> 7);                            // 128 float4 per row
  float d = den[row] + den[NN + row] + den[2 * NN + row] + den[3 * NN + row];
  const float4* nv = (const float4*)num;
  const size_t stride = (size_t)NN * DD / 4;
  float4 s0 = nv[idx];
  float4 s1 = nv[stride + idx];
  float4 s2 = nv[2 * stride + idx];
  float4 s3 = nv[3 * stride + idx];
  float4 s;
  s.x = s0.x + s1.x + s2.x + s3.x;
  s.y = s0.y + s1.y + s2.y + s3.y;
  s.z = s0.z + s1.z + s2.z + s3.z;
  s.w = s0.w + s1.w + s2.w + s3.w;
  const float inv = (d > 0.f) ? 1.f / d : 0.f;
  float4 o;
  o.x = 1.f - 2.f / (__expf(2.f * (s.x * inv)) + 1.f);
  o.y = 1.f - 2.f / (__expf(2.f * (s.y * inv)) + 1.f);
  o.z = 1.f - 2.f / (__expf(2.f * (s.z * inv)) + 1.f);
  o.w = 1.f - 2.f / (__expf(2.f * (s.w * inv)) + 1.f);
  ((float4*)out)[idx] = o;
}

// ----------------------------------------------------------------
extern "C" void kernel_launch(void* const* d_in, const int* in_sizes, int n_in,
                              void* d_out, int out_size, void* d_ws, size_t ws_size,
                              hipStream_t stream) {
  const float* input = (const float*)d_in[0];
  const float* adj   = (const float*)d_in[1];
  const float* W     = (const float*)d_in[2];
  const float* a1    = (const float*)d_in[3];
  const float* a2    = (const float*)d_in[4];
  float* out = (float*)d_out;
  char* ws = (char*)d_ws;

  // Persistent (live into k_fused/k_combine):
  u16* hT       = (u16*)ws;                       // 8192*512*2  = 8,388,608
  float* e1     = (float*)(ws + 8388608);         // 32,768
  float* e2     = (float*)(ws + 8421376);         // 32,768
  unsigned* mx  = (unsigned*)(ws + 8454144);      // 4 (pad to 256)
  float* denp   = (float*)(ws + 8454400);         // SPLIT*8192*4 = 131,072
  float* nump   = (float*)(ws + 8650752);         // SPLIT*8192*512*4 = 67,108,864 -> end 75,759,616
  // Transients (dead before k_fused writes nump) overlay the nump region:
  u16* input_bf = (u16*)(ws + 8650752);           // 8,388,608
  u16* WT       = (u16*)(ws + 8650752 + 8388608); // 524,288
  float* hbuf   = (float*)(ws + 8650752 + 8912896); // 16,777,216  (ends within nump)

  hipLaunchKernelGGL(k_convert_input, dim3(4096), dim3(256), 0, stream, input, input_bf);
  hipLaunchKernelGGL(k_convert_W, dim3(128), dim3(256), 0, stream, W, WT, mx);
  hipLaunchKernelGGL(k_gemm_h, dim3(64, 4), dim3(256), 0, stream, input_bf, WT, hbuf);
  hipLaunchKernelGGL(k_e12, dim3(2048), dim3(256), 0, stream, hbuf, a1, a2, e1, e2, mx);
  hipLaunchKernelGGL(k_transpose, dim3(256, 16), dim3(256), 0, stream, hbuf, hT);
  hipLaunchKernelGGL(k_fused, dim3(256, SPLIT), dim3(512), 0, stream, adj, hT, e1, e2, mx, nump, denp);
  hipLaunchKernelGGL(k_combine, dim3(4096), dim3(256), 0, stream, nump, denp, out);
}

// Round 3
// 429.600 us; speedup vs baseline: 1.5665x; 1.5665x over previous
//
#include <hip/hip_runtime.h>
#include <stdint.h>

#define NN 8192
#define DD 512
#define SPLIT 4
#define ITERS_PER_SPLIT 16   // 64 total K-iters of 128 / SPLIT

typedef uint16_t u16;
typedef __bf16 bf16x8_t __attribute__((ext_vector_type(8)));
typedef float f32x4_t __attribute__((ext_vector_type(4)));

__device__ __forceinline__ u16 f2bf(float x) {
  uint32_t u = __builtin_bit_cast(uint32_t, x);
  u += 0x7FFFu + ((u >> 16) & 1u);   // round-to-nearest-even
  return (u16)(u >> 16);
}

__device__ __forceinline__ unsigned encf(float f) {
  unsigned u = __builtin_bit_cast(unsigned, f);
  return (u & 0x80000000u) ? ~u : (u | 0x80000000u);
}
__device__ __forceinline__ float decf(unsigned e) {
  unsigned u = (e & 0x80000000u) ? (e & 0x7FFFFFFFu) : ~e;
  return __builtin_bit_cast(float, u);
}

// ---------------------------------------------------------------- convert input f32 -> bf16
__global__ __launch_bounds__(256) void k_convert_input(const float* __restrict__ in,
                                                       u16* __restrict__ out) {
  int idx = blockIdx.x * blockDim.x + threadIdx.x;  // one per 4 elems
  float4 v = ((const float4*)in)[idx];
  ushort4 o;
  o.x = f2bf(v.x); o.y = f2bf(v.y); o.z = f2bf(v.z); o.w = f2bf(v.w);
  ((ushort4*)out)[idx] = o;
}

// ---------------------------------------------------------------- W[k][n] -> WT[n][k] bf16, init maxenc
__global__ __launch_bounds__(256) void k_convert_W(const float* __restrict__ W,
                                                   u16* __restrict__ WT,
                                                   unsigned* __restrict__ maxenc) {
  int t = blockIdx.x * blockDim.x + threadIdx.x;  // 32768 threads
  if (t == 0) *maxenc = 0u;
  int n = t >> 6;
  int k8 = (t & 63) << 3;
  u16 tmp[8];
#pragma unroll
  for (int j = 0; j < 8; ++j) tmp[j] = f2bf(W[(size_t)(k8 + j) * DD + n]);
  uint32_t w0 = (uint32_t)tmp[0] | ((uint32_t)tmp[1] << 16);
  uint32_t w1 = (uint32_t)tmp[2] | ((uint32_t)tmp[3] << 16);
  uint32_t w2 = (uint32_t)tmp[4] | ((uint32_t)tmp[5] << 16);
  uint32_t w3 = (uint32_t)tmp[6] | ((uint32_t)tmp[7] << 16);
  *(uint4*)&WT[(size_t)n * DD + k8] = make_uint4(w0, w1, w2, w3);
}

// ---------------------------------------------------------------- h = input @ W  (bf16 MFMA, f32 out)
__global__ __launch_bounds__(256) void k_gemm_h(const u16* __restrict__ A,
                                                const u16* __restrict__ BT,
                                                float* __restrict__ H) {
  __shared__ __align__(16) u16 As[128 * 32];
  __shared__ __align__(16) u16 Bs[128 * 32];
  const int tid = threadIdx.x;
  const int wid = tid >> 6, lane = tid & 63;
  const int wr = wid >> 1, wc = wid & 1;
  const int lr = lane & 15, kg = lane >> 4;
  const int rowBase = blockIdx.x * 128;
  const int colBase = blockIdx.y * 128;
  const int sr = tid >> 2, sc = tid & 3;
  f32x4_t acc[4][4] = {};
  for (int kt = 0; kt < 16; ++kt) {
    const int k0 = kt * 32 + sc * 8;
    *(uint4*)&As[tid * 8] = *(const uint4*)&A[(size_t)(rowBase + sr) * DD + k0];
    *(uint4*)&Bs[tid * 8] = *(const uint4*)&BT[(size_t)(colBase + sr) * DD + k0];
    *(uint4*)&As[(tid + 256) * 8] = *(const uint4*)&A[(size_t)(rowBase + 64 + sr) * DD + k0];
    *(uint4*)&Bs[(tid + 256) * 8] = *(const uint4*)&BT[(size_t)(colBase + 64 + sr) * DD + k0];
    __syncthreads();
    bf16x8_t af[4], bfv[4];
#pragma unroll
    for (int mt = 0; mt < 4; ++mt)
      af[mt] = *(const bf16x8_t*)&As[(wr * 64 + mt * 16 + lr) * 32 + kg * 8];
#pragma unroll
    for (int nt = 0; nt < 4; ++nt)
      bfv[nt] = *(const bf16x8_t*)&Bs[(wc * 64 + nt * 16 + lr) * 32 + kg * 8];
#pragma unroll
    for (int mt = 0; mt < 4; ++mt)
#pragma unroll
      for (int nt = 0; nt < 4; ++nt)
        acc[mt][nt] = __builtin_amdgcn_mfma_f32_16x16x32_bf16(af[mt], bfv[nt], acc[mt][nt], 0, 0, 0);
    __syncthreads();
  }
#pragma unroll
  for (int mt = 0; mt < 4; ++mt)
#pragma unroll
    for (int nt = 0; nt < 4; ++nt)
#pragma unroll
      for (int r = 0; r < 4; ++r)
        H[(size_t)(rowBase + wr * 64 + mt * 16 + kg * 4 + r) * DD + colBase + wc * 64 + nt * 16 + lr] =
            acc[mt][nt][r];
}

// ---------------------------------------------------------------- e1/e2 per row (f32), maxE2 via encoded atomicMax
__global__ __launch_bounds__(256) void k_e12(const float* __restrict__ H,
                                             const float* __restrict__ a1,
                                             const float* __restrict__ a2,
                                             float* __restrict__ e1, float* __restrict__ e2,
                                             unsigned* __restrict__ maxenc) {
  const int wid = threadIdx.x >> 6, lane = threadIdx.x & 63;
  const int row = blockIdx.x * 4 + wid;
  const float* hr = H + (size_t)row * DD;
  float s1 = 0.f, s2 = 0.f;
#pragma unroll
  for (int base = 0; base < DD; base += 256) {
    float4 hv = *(const float4*)&hr[base + lane * 4];
    float4 v1 = *(const float4*)&a1[base + lane * 4];
    float4 v2 = *(const float4*)&a2[base + lane * 4];
    s1 += hv.x * v1.x + hv.y * v1.y + hv.z * v1.z + hv.w * v1.w;
    s2 += hv.x * v2.x + hv.y * v2.y + hv.z * v2.z + hv.w * v2.w;
  }
#pragma unroll
  for (int off = 32; off >= 1; off >>= 1) {
    s1 += __shfl_down(s1, off);
    s2 += __shfl_down(s2, off);
  }
  if (lane == 0) {
    e1[row] = s1;
    e2[row] = s2;
    atomicMax(maxenc, encf(s2));
  }
}

// ---------------------------------------------------------------- H f32 [8192][512] -> HT bf16 [512][8192]
__global__ __launch_bounds__(256) void k_transpose(const float* __restrict__ H,
                                                   u16* __restrict__ HT) {
  __shared__ float tile[32][33];
  const int r0 = blockIdx.x * 32;
  const int c0 = blockIdx.y * 32;
  const int tx = threadIdx.x & 31;
  const int ty = threadIdx.x >> 5;  // 0..7
#pragma unroll
  for (int i = 0; i < 4; ++i) {
    int r = ty + i * 8;
    tile[r][tx] = H[(size_t)(r0 + r) * DD + c0 + tx];
  }
  __syncthreads();
#pragma unroll
  for (int i = 0; i < 4; ++i) {
    int c = ty + i * 8;
    HT[(size_t)(c0 + c) * NN + r0 + tx] = f2bf(tile[tx][c]);
  }
}

// ---------------------------------------------------------------- fused masked-softmax @ h (split-K partials)
// grid (256, SPLIT) x 512 threads. Block owns 32 rows x 2048 K-cols (16 iters of 128).
// P stored in LDS in MFMA-fragment-linear order: unit tau = mt*256 + c*16 + m  (c = ks*4+kg),
// so both ds_write (tau = tid) and ds_read (addr = mt*4096 + ks*1024 + lane*16) are linear.
// NOTE: no min-waves pin here — __launch_bounds__(512,8) forced VGPR<=64 and spilled acc
// to scratch (R2: VGPR 56->32, WRITE_SIZE 16MB->794MB, 353->575us). 56 VGPR already
// allows 8 waves/SIMD; the SPLIT=4 grid provides the 4 co-resident blocks/CU.
__global__ __launch_bounds__(512) void k_fused(const float* __restrict__ adj,
                                               const u16* __restrict__ HT,
                                               const float* __restrict__ e1,
                                               const float* __restrict__ e2,
                                               const unsigned* __restrict__ maxenc,
                                               float* __restrict__ numpart,
                                               float* __restrict__ denpart) {
  __shared__ __align__(16) u16 P[2][32 * 128];
  __shared__ float partsum[512];
  const int tid = threadIdx.x;
  const int wid = tid >> 6;
  const int lane = tid & 63;
  const int lr = lane & 15;
  const int kg = lane >> 4;
  const int rowBase = blockIdx.x * 32;
  const int bz = blockIdx.y;
  const int kk0 = bz * ITERS_PER_SPLIT;
  // P-build task coords (fixed per thread; each thread owns one row's 8-col slab per iter)
  const int pmt = tid >> 8;        // 0..1
  const int pc = (tid >> 4) & 15;  // 0..15 -> 8-col chunk
  const int pm = tid & 15;
  const int prow = rowBase + pmt * 16 + pm;
  const float e1r = e1[prow];
  const float mE2 = decf(*maxenc);
  const float xb = e1r + mE2;
  const float bnd = fmaxf(xb, 0.2f * xb);  // leakyrelu(e1+maxE2) >= all row scores
  float dsum = 0.f;
  const float* adjp = adj + (size_t)prow * NN + pc * 8;
  const float* e2p = e2 + pc * 8;
  const int n0 = wid * 64;
  const u16* btp0 = HT + (size_t)(n0 + 0 + lr) * NN + kg * 8;
  const u16* btp1 = HT + (size_t)(n0 + 16 + lr) * NN + kg * 8;
  const u16* btp2 = HT + (size_t)(n0 + 32 + lr) * NN + kg * 8;
  const u16* btp3 = HT + (size_t)(n0 + 48 + lr) * NN + kg * 8;
  f32x4_t acc[2][4] = {};
  for (int t = 0; t < ITERS_PER_SPLIT; ++t) {
    const int kk = kk0 + t;
    const int colBase = kk * 128;
    float4 av0 = *(const float4*)(adjp + colBase);
    float4 av1 = *(const float4*)(adjp + colBase + 4);
    float4 ev0 = *(const float4*)(e2p + colBase);
    float4 ev1 = *(const float4*)(e2p + colBase + 4);
    float aa[8] = {av0.x, av0.y, av0.z, av0.w, av1.x, av1.y, av1.z, av1.w};
    float ee[8] = {ev0.x, ev0.y, ev0.z, ev0.w, ev1.x, ev1.y, ev1.z, ev1.w};
    float pv[8];
#pragma unroll
    for (int j = 0; j < 8; ++j) {
      float x = e1r + ee[j];
      float s = fmaxf(x, 0.2f * x);                       // leakyrelu
      float p = (aa[j] > -1e19f) ? __expf(s - bnd) : 0.f; // mask: adj==0 means edge
      pv[j] = p;
      dsum += p;
    }
    uint32_t w0 = (uint32_t)f2bf(pv[0]) | ((uint32_t)f2bf(pv[1]) << 16);
    uint32_t w1 = (uint32_t)f2bf(pv[2]) | ((uint32_t)f2bf(pv[3]) << 16);
    uint32_t w2 = (uint32_t)f2bf(pv[4]) | ((uint32_t)f2bf(pv[5]) << 16);
    uint32_t w3 = (uint32_t)f2bf(pv[6]) | ((uint32_t)f2bf(pv[7]) << 16);
    *(uint4*)&P[t & 1][tid * 8] = make_uint4(w0, w1, w2, w3);
    __syncthreads();
    const u16* pb = &P[t & 1][0];
#pragma unroll
    for (int ks = 0; ks < 4; ++ks) {
      bf16x8_t a0 = *(const bf16x8_t*)(pb + ks * 512 + lane * 8);
      bf16x8_t a1f = *(const bf16x8_t*)(pb + 2048 + ks * 512 + lane * 8);
      const int co = colBase + ks * 32;
      bf16x8_t b0 = *(const bf16x8_t*)(btp0 + co);
      bf16x8_t b1 = *(const bf16x8_t*)(btp1 + co);
      bf16x8_t b2 = *(const bf16x8_t*)(btp2 + co);
      bf16x8_t b3 = *(const bf16x8_t*)(btp3 + co);
      acc[0][0] = __builtin_amdgcn_mfma_f32_16x16x32_bf16(a0, b0, acc[0][0], 0, 0, 0);
      acc[0][1] = __builtin_amdgcn_mfma_f32_16x16x32_bf16(a0, b1, acc[0][1], 0, 0, 0);
      acc[0][2] = __builtin_amdgcn_mfma_f32_16x16x32_bf16(a0, b2, acc[0][2], 0, 0, 0);
      acc[0][3] = __builtin_amdgcn_mfma_f32_16x16x32_bf16(a0, b3, acc[0][3], 0, 0, 0);
      acc[1][0] = __builtin_amdgcn_mfma_f32_16x16x32_bf16(a1f, b0, acc[1][0], 0, 0, 0);
      acc[1][1] = __builtin_amdgcn_mfma_f32_16x16x32_bf16(a1f, b1, acc[1][1], 0, 0, 0);
      acc[1][2] = __builtin_amdgcn_mfma_f32_16x16x32_bf16(a1f, b2, acc[1][2], 0, 0, 0);
      acc[1][3] = __builtin_amdgcn_mfma_f32_16x16x32_bf16(a1f, b3, acc[1][3], 0, 0, 0);
    }
  }
  // deterministic per-row denominator reduction (16 partials per row, fixed order)
  partsum[tid] = dsum;
  __syncthreads();
  if (tid < 32) {
    const int emt = tid >> 4, em = tid & 15;
    float s = 0.f;
#pragma unroll
    for (int cc = 0; cc < 16; ++cc) s += partsum[emt * 256 + cc * 16 + em];
    denpart[(size_t)bz * NN + rowBase + tid] = s;
  }
  float* np = numpart + (size_t)bz * NN * DD;
#pragma unroll
  for (int mt = 0; mt < 2; ++mt)
#pragma unroll
    for (int nt = 0; nt < 4; ++nt)
#pragma unroll
      for (int r = 0; r < 4; ++r) {
        const int rowL = mt * 16 + kg * 4 + r;
        np[(size_t)(rowBase + rowL) * DD + n0 + nt * 16 + lr] = acc[mt][nt][r];
      }
}

// ---------------------------------------------------------------- combine partials: out = tanh(num/den)
__global__ __launch_bounds__(256) void k_combine(const float* __restrict__ num,
                                                 const float* __restrict__ den,
                                                 float* __restrict__ out) {
  const size_t idx = (size_t)blockIdx.x * 256 + threadIdx.x;  // float4 units
  const int row = (int)(idx >> 7);                            // 128 float4 per row
  float d = den[row] + den[NN + row] + den[2 * NN + row] + den[3 * NN + row];
  const float4* nv = (const float4*)num;
  const size_t stride = (size_t)NN * DD / 4;
  float4 s0 = nv[idx];
  float4 s1 = nv[stride + idx];
  float4 s2 = nv[2 * stride + idx];
  float4 s3 = nv[3 * stride + idx];
  float4 s;
  s.x = s0.x + s1.x + s2.x + s3.x;
  s.y = s0.y + s1.y + s2.y + s3.y;
  s.z = s0.z + s1.z + s2.z + s3.z;
  s.w = s0.w + s1.w + s2.w + s3.w;
  const float inv = (d > 0.f) ? 1.f / d : 0.f;
  float4 o;
  o.x = 1.f - 2.f / (__expf(2.f * (s.x * inv)) + 1.f);
  o.y = 1.f - 2.f / (__expf(2.f * (s.y * inv)) + 1.f);
  o.z = 1.f - 2.f / (__expf(2.f * (s.z * inv)) + 1.f);
  o.w = 1.f - 2.f / (__expf(2.f * (s.w * inv)) + 1.f);
  ((float4*)out)[idx] = o;
}

// ----------------------------------------------------------------
extern "C" void kernel_launch(void* const* d_in, const int* in_sizes, int n_in,
                              void* d_out, int out_size, void* d_ws, size_t ws_size,
                              hipStream_t stream) {
  const float* input = (const float*)d_in[0];
  const float* adj   = (const float*)d_in[1];
  const float* W     = (const float*)d_in[2];
  const float* a1    = (const float*)d_in[3];
  const float* a2    = (const float*)d_in[4];
  float* out = (float*)d_out;
  char* ws = (char*)d_ws;

  // Persistent (live into k_fused/k_combine):
  u16* hT       = (u16*)ws;                       // 8192*512*2  = 8,388,608
  float* e1     = (float*)(ws + 8388608);         // 32,768
  float* e2     = (float*)(ws + 8421376);         // 32,768
  unsigned* mx  = (unsigned*)(ws + 8454144);      // 4 (pad to 256)
  float* denp   = (float*)(ws + 8454400);         // SPLIT*8192*4 = 131,072
  float* nump   = (float*)(ws + 8650752);         // SPLIT*8192*512*4 = 67,108,864 -> end 75,759,616
  // Transients (dead before k_fused writes nump) overlay the nump region:
  u16* input_bf = (u16*)(ws + 8650752);           // 8,388,608
  u16* WT       = (u16*)(ws + 8650752 + 8388608); // 524,288
  float* hbuf   = (float*)(ws + 8650752 + 8912896); // 16,777,216  (ends within nump)

  hipLaunchKernelGGL(k_convert_input, dim3(4096), dim3(256), 0, stream, input, input_bf);
  hipLaunchKernelGGL(k_convert_W, dim3(128), dim3(256), 0, stream, W, WT, mx);
  hipLaunchKernelGGL(k_gemm_h, dim3(64, 4), dim3(256), 0, stream, input_bf, WT, hbuf);
  hipLaunchKernelGGL(k_e12, dim3(2048), dim3(256), 0, stream, hbuf, a1, a2, e1, e2, mx);
  hipLaunchKernelGGL(k_transpose, dim3(256, 16), dim3(256), 0, stream, hbuf, hT);
  hipLaunchKernelGGL(k_fused, dim3(256, SPLIT), dim3(512), 0, stream, adj, hT, e1, e2, mx, nump, denp);
  hipLaunchKernelGGL(k_combine, dim3(4096), dim3(256), 0, stream, nump, denp, out);
}